// Round 6
// baseline (952.064 us; speedup 1.0000x reference)
//
#include <hip/hip_runtime.h>
#include <stdint.h>

// LiquidStateMachine on MI355X — round 6.
// r5 established: LDS gather pipe is the wall (~174us), ~45% of it bank
// conflicts (spike records at k*16 -> only 8 distinct bank-starts).
// r6: (1) SWIZZLED spike layout f(k) = 16k + 4*(k>>3) -> 32 uniform
// bank-starts, ~2 lanes/bank (free). Swizzle is FREE at runtime because
// gather addresses are precomputed into the entry stream. (2) Entry =
// {u32 byte-offset, f32 weight} interleaved 8+8 per 64B lane record ->
// 4 contiguous dwordx4 loads/iter, zero unpack VALU, load->ds_read direct.
// Weights remain EXACT fp32 (r2: any weight rounding flips spikes through
// the recurrent threshold); f16 spike 0/1 exact; only summation order
// differs from reference.
//
// d_ws layout (bytes):
//   0      PERM[512]  sorted-rank -> column
//   2048   RANK[512]  column -> sorted rank
//   4096   CNT[512]   nnz per column          (zeroed via hipMemsetAsync)
//   8192   CNTW[8]    per-group padded trip count (multiple of 16)
//   8256   EBASE[8]   per-group byte base into ENT region
//   16384  ENT        per chunk (8 entries) per lane: 64 B =
//                     [0,32) 8x u32 spike-offsets, [32,64) 8x f32 weights
//                     byte = eb + (j>>3)*4096 + ls*64 + (j&7)*4 (+32 for w)

#define N_NEU 512
#define B_ROWS 2048
#define D_IN 256
#define R_PB 8
#define NBLK (B_ROWS / R_PB)   // 256 blocks x 1024 threads = 1 block/CU

#define WS_PERM    0
#define WS_RANK    2048
#define WS_CNT     4096
#define WS_CNTW    8192
#define WS_EBASE   8256
#define WS_ENT     16384

// swizzled spike-record byte offset for neuron k (16B record, +4B skew/8)
#define SPK_OFF(k) (((k) << 4) + (((k) >> 3) << 2))
#define SPK_BYTES  (SPK_OFF(N_NEU - 1) + 16)   // 8444 -> round up to 8448

typedef _Float16 half8 __attribute__((ext_vector_type(8)));

// ---------------------------------------------------------------- prep A
__global__ __launch_bounds__(256) void lsm_count(
    const float* __restrict__ W, uint32_t* __restrict__ ws)
{
    int t  = threadIdx.x;
    int k0 = blockIdx.x * 4;
    int c0 = 0, c1 = 0;
    #pragma unroll
    for (int kk = 0; kk < 4; ++kk) {
        const float* row = W + (size_t)(k0 + kk) * N_NEU;
        c0 += (row[t]       != 0.0f) ? 1 : 0;
        c1 += (row[t + 256] != 0.0f) ? 1 : 0;
    }
    if (c0) atomicAdd(&ws[(WS_CNT >> 2) + t],       (uint32_t)c0);
    if (c1) atomicAdd(&ws[(WS_CNT >> 2) + t + 256], (uint32_t)c1);
}

// ---------------------------------------------------------------- prep B
// Counting-sort columns ascending by nnz; per-group padded trip counts
// (multiple of 16: both stream-halves get whole 8-entry chunks) + bases;
// pad tail entries (offset 0 -> reads neuron 0's record, w=0.0f -> adds 0).
__global__ __launch_bounds__(512) void lsm_sort(uint32_t* __restrict__ ws)
{
    __shared__ int hist[N_NEU + 1];
    __shared__ int csort[N_NEU];
    __shared__ int gcw[8];

    int t = threadIdx.x;
    int creal = (int)ws[(WS_CNT >> 2) + t];
    for (int i = t; i < N_NEU + 1; i += 512) hist[i] = 0;
    __syncthreads();
    atomicAdd(&hist[creal], 1);
    __syncthreads();
    if (t == 0) {
        int acc = 0;
        for (int v = 0; v <= N_NEU; ++v) { int h = hist[v]; hist[v] = acc; acc += h; }
    }
    __syncthreads();
    int rank = atomicAdd(&hist[creal], 1);
    ws[(WS_PERM >> 2) + rank] = (uint32_t)t;
    ws[(WS_RANK >> 2) + t]    = (uint32_t)rank;
    csort[rank] = creal;
    __syncthreads();
    if (t < 8) {
        int cw = csort[t * 64 + 63];         // ascending -> group max is last
        cw = (cw + 15) & ~15;                // pad to multiple of 16
        gcw[t] = cw;
        ws[(WS_CNTW >> 2) + t] = (uint32_t)cw;
    }
    __syncthreads();
    if (t == 0) {
        int ae = 0;
        for (int g = 0; g < 8; ++g) {
            ws[(WS_EBASE >> 2) + g] = (uint32_t)ae;
            ae += gcw[g] * 64 * 8;           // bytes: 8 B/entry x 64 lanes
        }
    }
    __syncthreads();
    // pad tail slots of this thread's column
    int wg = rank >> 6, ls = rank & 63;
    int cw = gcw[wg];
    uint32_t eb = ws[(WS_EBASE >> 2) + wg];
    char* base = (char*)ws + WS_ENT;
    for (int j = creal; j < cw; ++j) {
        char* rec = base + eb + (j >> 3) * 4096 + ls * 64 + (j & 7) * 4;
        *(uint32_t*)rec      = 0u;       // gather neuron 0's record
        *(float*)(rec + 32)  = 0.0f;     // weight 0 -> harmless
    }
}

// ---------------------------------------------------------------- prep C
// One block per COLUMN, LDS-local cursor. Index stored as FINAL swizzled
// LDS byte offset of neuron k's spike record -> zero address math in main.
__global__ __launch_bounds__(64) void lsm_fill(
    const float* __restrict__ W, uint32_t* __restrict__ ws)
{
    int c    = blockIdx.x;
    int lane = threadIdx.x;
    uint32_t rank = ws[(WS_RANK >> 2) + c];
    int wg = (int)(rank >> 6), ls = (int)(rank & 63);
    uint32_t eb = ws[(WS_EBASE >> 2) + wg];
    char* base = (char*)ws + WS_ENT;

    __shared__ int ctr;
    if (lane == 0) ctr = 0;
    __syncthreads();

    for (int k = lane; k < N_NEU; k += 64) {
        float wv = W[(size_t)k * N_NEU + c];
        if (wv != 0.0f) {
            int j = atomicAdd(&ctr, 1);      // order within column irrelevant
            char* rec = base + eb + (j >> 3) * 4096 + ls * 64 + (j & 7) * 4;
            *(uint32_t*)rec     = (uint32_t)SPK_OFF(k);
            *(float*)(rec + 32) = wv;
        }
    }
}

// ---------------------------------------------------------------- main
// LDS map:
//   [0,8448)       spk : f16 [8 rows] per neuron, swizzled 16B records
//                  (at offset 0 so gather addr == precomputed stream value)
//   [8448,24832)   recx: float[512 cols][8] (half-1 partial rec)
//                  rl  : overlay at 8448, rates staging [8][256] (pre-loop)
__global__ __launch_bounds__(1024, 4) void lsm_main(
    const float* __restrict__ rates, const float* __restrict__ inW,
    const float* __restrict__ vin,   const float* __restrict__ cin,
    const int* __restrict__ nsteps_p,
    const uint32_t* __restrict__ ws, float* __restrict__ out)
{
    __shared__ __align__(16) unsigned char smem[8448 + 16384];
    float* recx = (float*)(smem + 8448);
    float* rl   = (float*)(smem + 8448);         // overlay, pre-loop only

    int p    = threadIdx.x;
    int h    = p >> 9;          // stream half: 0 or 1
    int q    = p & 511;         // column slot
    int blk  = blockIdx.x;
    int r0   = blk * R_PB;
    int wg   = q >> 6;
    int lane = q & 63;
    int n    = (int)ws[(WS_PERM >> 2) + q];
    int cw   = (int)ws[(WS_CNTW >> 2) + wg];     // wave-uniform
    int nit  = cw >> 4;                          // 8-entry chunks per half
    const char* ep0 = (const char*)ws + WS_ENT + ws[(WS_EBASE >> 2) + wg]
                    + h * 4096 + lane * 64;

    // stage this block's 8 rate rows (2048 floats = 512 float4)
    if (p < 512)
        ((float4*)rl)[p] = ((const float4*)(rates + (size_t)r0 * D_IN))[p];
    __syncthreads();

    float c0v[R_PB], v0v[R_PB], ssum[R_PB], I[R_PB];
    if (h == 0) {
        // input current I[r] = rates[r,:] . inW[n,:] (constant across steps)
        #pragma unroll
        for (int r = 0; r < R_PB; ++r) I[r] = 0.f;
        const float4* wrow = (const float4*)(inW + (size_t)n * D_IN);
        for (int d4 = 0; d4 < D_IN / 4; ++d4) {
            float4 wv = wrow[d4];
            #pragma unroll
            for (int r = 0; r < R_PB; ++r) {
                const float* rr = rl + r * D_IN + d4 * 4;   // LDS broadcast
                I[r] += wv.x * rr[0] + wv.y * rr[1] + wv.z * rr[2] + wv.w * rr[3];
            }
        }
        // state load + initial f16 spikes
        half8 s0;
        #pragma unroll
        for (int r = 0; r < R_PB; ++r) {
            c0v[r] = cin[(size_t)(r0 + r) * N_NEU + n];
            v0v[r] = vin[(size_t)(r0 + r) * N_NEU + n];
            ssum[r] = 0.f;
            s0[r] = (c0v[r] > 0.f) ? (_Float16)1 : (_Float16)0;
        }
        __syncthreads();   // rl reads done before spk writes reuse nothing,
                           // but keep ordering vs recx region reuse
        *(half8*)(smem + SPK_OFF(n)) = s0;
    } else {
        __syncthreads();   // matching barrier
    }

    const float AS   = (float)0.8187307530779818;   // exp(-1/5)
    const float OMAS = (float)(1.0 - 0.8187307530779818);
    const float AM   = (float)0.9512294245007140;   // exp(-1/20)
    const float OMAM = (float)(1.0 - 0.9512294245007140);

    int T = nsteps_p[0];
    __syncthreads();

    #pragma unroll 1
    for (int t = 0; t < T; ++t) {
        float rec[R_PB];
        #pragma unroll
        for (int r = 0; r < R_PB; ++r) rec[r] = 0.f;

        const char* ep = ep0;
        #pragma unroll 2
        for (int it = 0; it < nit; ++it) {
            uint4  X0 = ((const uint4*)ep)[0];       // 4 spike offsets
            uint4  X1 = ((const uint4*)ep)[1];       // 4 spike offsets
            float4 Wa = ((const float4*)(ep + 32))[0];   // 8 exact f32 weights
            float4 Wb = ((const float4*)(ep + 32))[1];
            ep += 8192;
            half8 s0 = *(const half8*)(smem + X0.x);
            half8 s1 = *(const half8*)(smem + X0.y);
            half8 s2 = *(const half8*)(smem + X0.z);
            half8 s3 = *(const half8*)(smem + X0.w);
            half8 s4 = *(const half8*)(smem + X1.x);
            half8 s5 = *(const half8*)(smem + X1.y);
            half8 s6 = *(const half8*)(smem + X1.z);
            half8 s7 = *(const half8*)(smem + X1.w);
            #pragma unroll
            for (int r = 0; r < R_PB; ++r) {
                float a = rec[r];
                a = fmaf(Wa.x, (float)s0[r], a);
                a = fmaf(Wa.y, (float)s1[r], a);
                a = fmaf(Wa.z, (float)s2[r], a);
                a = fmaf(Wa.w, (float)s3[r], a);
                a = fmaf(Wb.x, (float)s4[r], a);
                a = fmaf(Wb.y, (float)s5[r], a);
                a = fmaf(Wb.z, (float)s6[r], a);
                a = fmaf(Wb.w, (float)s7[r], a);
                rec[r] = a;
            }
        }

        if (h == 1) {
            float* rx = recx + (size_t)q * 8;
            *(float4*)rx       = make_float4(rec[0], rec[1], rec[2], rec[3]);
            *(float4*)(rx + 4) = make_float4(rec[4], rec[5], rec[6], rec[7]);
        }
        __syncthreads();   // half-1 partials visible; all spike reads done

        if (h == 0) {
            const float* rx = recx + (size_t)q * 8;
            half8 ns;
            #pragma unroll
            for (int r = 0; r < R_PB; ++r) {
                float rc = rec[r] + rx[r];
                c0v[r] = AS * c0v[r] + OMAS * (I[r] + rc);
                v0v[r] = AM * v0v[r] + OMAM * c0v[r];
                ssum[r] += (v0v[r] > 0.f) ? 1.f : 0.f;
                ns[r] = (c0v[r] > 0.f) ? (_Float16)1 : (_Float16)0;
            }
            *(half8*)(smem + SPK_OFF(n)) = ns;
        }
        __syncthreads();   // new spikes visible
    }

    if (h == 0) {
        float invT = 1.0f / (float)T;
        size_t BN = (size_t)B_ROWS * N_NEU;
        #pragma unroll
        for (int r = 0; r < R_PB; ++r) {
            size_t off = (size_t)(r0 + r) * N_NEU + n;
            out[off]          = ssum[r] * invT;   // readout
            out[BN + off]     = v0v[r];           // final v
            out[2 * BN + off] = c0v[r];           // final c
        }
    }
}

// ---------------------------------------------------------------- launch
extern "C" void kernel_launch(void* const* d_in, const int* in_sizes, int n_in,
                              void* d_out, int out_size, void* d_ws, size_t ws_size,
                              hipStream_t stream)
{
    const float* rates = (const float*)d_in[0];
    const float* inW   = (const float*)d_in[1];
    const float* W     = (const float*)d_in[2];
    const float* vin   = (const float*)d_in[3];
    const float* cin   = (const float*)d_in[4];
    const int*   nst   = (const int*)d_in[5];
    uint32_t* ws = (uint32_t*)d_ws;
    float* out = (float*)d_out;
    (void)in_sizes; (void)n_in; (void)out_size; (void)ws_size;

    // zero CNT (harness poisons d_ws to 0xAA before every call)
    hipMemsetAsync((char*)d_ws + WS_CNT, 0, 2048, stream);

    lsm_count<<<128, 256, 0, stream>>>(W, ws);
    lsm_sort<<<1, 512, 0, stream>>>(ws);
    lsm_fill<<<N_NEU, 64, 0, stream>>>(W, ws);
    lsm_main<<<NBLK, 1024, 0, stream>>>(rates, inW, vin, cin, nst, ws, out);
}

// Round 7
// 941.747 us; speedup vs baseline: 1.0110x; 1.0110x over previous
//
#include <hip/hip_runtime.h>
#include <stdint.h>

// LiquidStateMachine on MI355X — round 7.
// r5 (366us) = separate lane-coalesced streams; LDS-gather bound, 45% bank
// conflicts. r6 proved the swizzle kills conflicts (4.85e7->5.6e6) but its
// 64B/lane interleaved record made every vmem load a stride-64 gather
// (64 cache lines/instr) -> latency-bound 905us. r7 = r5's exact stream
// layout + swizzled u16 offsets (SPK_OFF(k) = 16k + 4*(k>>3) <= 8444 fits
// u16). Conflict fix now costs nothing.
// Weights EXACT fp32 (r2: rounding flips spikes); f16 spike 0/1 exact.
//
// d_ws layout (bytes):
//   0      PERM[512]  sorted-rank -> column
//   2048   RANK[512]  column -> sorted rank
//   4096   CNT[512]   nnz per column          (zeroed via hipMemsetAsync)
//   8192   CNTW[8]    per-group padded trip count (multiple of 16)
//   8256   IBASE[8]   per-group byte base into IDX region
//   8320   WBASE[8]   per-group byte base into WT region
//   16384  IDX        u16 swizzled spike-offset:
//                     byte = ib + (j>>3)*1024 + ls*16 + (j&7)*2
//   81920  WT         f32 w: byte = wb + (j>>3)*2048 + ls*32 + (j&7)*4

#define N_NEU 512
#define B_ROWS 2048
#define D_IN 256
#define R_PB 8
#define NBLK (B_ROWS / R_PB)   // 256 blocks x 1024 threads = 1 block/CU

#define WS_PERM    0
#define WS_RANK    2048
#define WS_CNT     4096
#define WS_CNTW    8192
#define WS_IBASE   8256
#define WS_WBASE   8320
#define WS_IDX     16384
#define WS_WT      81920

// swizzled spike-record byte offset for neuron k (16B record, +4B skew/8)
// bank-start = (4k + (k>>3)) mod 32 -> uniform over all 32 banks
#define SPK_OFF(k) (((k) << 4) + (((k) >> 3) << 2))
#define SPK_REGION 8448        // SPK_OFF(511)+16 = 8444, padded

typedef _Float16 half8 __attribute__((ext_vector_type(8)));

// ---------------------------------------------------------------- prep A
__global__ __launch_bounds__(256) void lsm_count(
    const float* __restrict__ W, uint32_t* __restrict__ ws)
{
    int t  = threadIdx.x;
    int k0 = blockIdx.x * 4;
    int c0 = 0, c1 = 0;
    #pragma unroll
    for (int kk = 0; kk < 4; ++kk) {
        const float* row = W + (size_t)(k0 + kk) * N_NEU;
        c0 += (row[t]       != 0.0f) ? 1 : 0;
        c1 += (row[t + 256] != 0.0f) ? 1 : 0;
    }
    if (c0) atomicAdd(&ws[(WS_CNT >> 2) + t],       (uint32_t)c0);
    if (c1) atomicAdd(&ws[(WS_CNT >> 2) + t + 256], (uint32_t)c1);
}

// ---------------------------------------------------------------- prep B
// Counting-sort columns ascending by nnz; per-group padded trip counts
// (multiple of 16: both stream-halves get whole 8-entry chunks) + bases;
// pad entries (offset 0 -> reads neuron 0's record, w=+0.0f -> adds 0).
__global__ __launch_bounds__(512) void lsm_sort(uint32_t* __restrict__ ws)
{
    __shared__ int hist[N_NEU + 1];
    __shared__ int csort[N_NEU];
    __shared__ int gcw[8];

    int t = threadIdx.x;
    int creal = (int)ws[(WS_CNT >> 2) + t];
    for (int i = t; i < N_NEU + 1; i += 512) hist[i] = 0;
    __syncthreads();
    atomicAdd(&hist[creal], 1);
    __syncthreads();
    if (t == 0) {
        int acc = 0;
        for (int v = 0; v <= N_NEU; ++v) { int h = hist[v]; hist[v] = acc; acc += h; }
    }
    __syncthreads();
    int rank = atomicAdd(&hist[creal], 1);
    ws[(WS_PERM >> 2) + rank] = (uint32_t)t;
    ws[(WS_RANK >> 2) + t]    = (uint32_t)rank;
    csort[rank] = creal;
    __syncthreads();
    if (t < 8) {
        int cw = csort[t * 64 + 63];         // ascending -> group max is last
        cw = (cw + 15) & ~15;                // pad to multiple of 16
        gcw[t] = cw;
        ws[(WS_CNTW >> 2) + t] = (uint32_t)cw;
    }
    __syncthreads();
    if (t == 0) {
        int ai = 0, aw = 0;
        for (int g = 0; g < 8; ++g) {
            ws[(WS_IBASE >> 2) + g] = (uint32_t)ai;
            ws[(WS_WBASE >> 2) + g] = (uint32_t)aw;
            ai += gcw[g] * 64 * 2;           // bytes (u16 per entry)
            aw += gcw[g] * 64 * 4;           // bytes (f32 per entry)
        }
    }
    __syncthreads();
    // pad tail slots of this thread's column
    int wg = rank >> 6, ls = rank & 63;
    int cw = gcw[wg];
    uint32_t ib = ws[(WS_IBASE >> 2) + wg];
    uint32_t wb = ws[(WS_WBASE >> 2) + wg];
    char* base = (char*)ws;
    for (int j = creal; j < cw; ++j) {
        *(unsigned short*)(base + WS_IDX + ib + (j >> 3) * 1024 + ls * 16 + (j & 7) * 2) = 0;
        *(float*)(base + WS_WT + wb + (j >> 3) * 2048 + ls * 32 + (j & 7) * 4) = 0.0f;
    }
}

// ---------------------------------------------------------------- prep C
// One block per COLUMN, LDS-local cursor. Index stored as FINAL swizzled
// LDS byte offset of neuron k's spike record -> zero address math in main.
__global__ __launch_bounds__(64) void lsm_fill(
    const float* __restrict__ W, uint32_t* __restrict__ ws)
{
    int c    = blockIdx.x;
    int lane = threadIdx.x;
    char* base = (char*)ws;
    uint32_t rank = ws[(WS_RANK >> 2) + c];
    int wg = (int)(rank >> 6), ls = (int)(rank & 63);
    uint32_t ib = ws[(WS_IBASE >> 2) + wg];
    uint32_t wb = ws[(WS_WBASE >> 2) + wg];

    __shared__ int ctr;
    if (lane == 0) ctr = 0;
    __syncthreads();

    for (int k = lane; k < N_NEU; k += 64) {
        float wv = W[(size_t)k * N_NEU + c];
        if (wv != 0.0f) {
            int j = atomicAdd(&ctr, 1);      // order within column irrelevant
            *(unsigned short*)(base + WS_IDX + ib + (j >> 3) * 1024 + ls * 16 + (j & 7) * 2)
                = (unsigned short)SPK_OFF(k);
            *(float*)(base + WS_WT + wb + (j >> 3) * 2048 + ls * 32 + (j & 7) * 4) = wv;
        }
    }
}

// ---------------------------------------------------------------- main
// LDS map:
//   [0,8448)       spk : f16 [8 rows] per neuron, swizzled 16B records
//                  (at offset 0 so gather addr == precomputed stream value)
//   [8448,24832)   recx: float[512 cols][8] (half-1 partial rec)
//                  rl  : overlay at 8448, rates staging [8][256] (pre-loop)
__global__ __launch_bounds__(1024, 4) void lsm_main(
    const float* __restrict__ rates, const float* __restrict__ inW,
    const float* __restrict__ vin,   const float* __restrict__ cin,
    const int* __restrict__ nsteps_p,
    const uint32_t* __restrict__ ws, float* __restrict__ out)
{
    __shared__ __align__(16) unsigned char smem[SPK_REGION + 16384];
    float* recx = (float*)(smem + SPK_REGION);
    float* rl   = (float*)(smem + SPK_REGION);   // overlay, pre-loop only

    int p    = threadIdx.x;
    int h    = p >> 9;          // stream half: 0 or 1
    int q    = p & 511;         // column slot
    int blk  = blockIdx.x;
    int r0   = blk * R_PB;
    int wg   = q >> 6;
    int lane = q & 63;
    int n    = (int)ws[(WS_PERM >> 2) + q];
    int cw   = (int)ws[(WS_CNTW >> 2) + wg];     // wave-uniform
    int nit  = cw >> 4;                          // 8-entry chunks per half
    const char* ip0 = (const char*)ws + WS_IDX + ws[(WS_IBASE >> 2) + wg]
                    + h * 1024 + lane * 16;
    const char* wp0 = (const char*)ws + WS_WT  + ws[(WS_WBASE >> 2) + wg]
                    + h * 2048 + lane * 32;
    int spk_n = SPK_OFF(n);                      // this column's record

    // stage this block's 8 rate rows (2048 floats = 512 float4)
    if (p < 512)
        ((float4*)rl)[p] = ((const float4*)(rates + (size_t)r0 * D_IN))[p];
    __syncthreads();

    float c0v[R_PB], v0v[R_PB], ssum[R_PB], I[R_PB];
    if (h == 0) {
        // input current I[r] = rates[r,:] . inW[n,:] (constant across steps)
        #pragma unroll
        for (int r = 0; r < R_PB; ++r) I[r] = 0.f;
        const float4* wrow = (const float4*)(inW + (size_t)n * D_IN);
        for (int d4 = 0; d4 < D_IN / 4; ++d4) {
            float4 wv = wrow[d4];
            #pragma unroll
            for (int r = 0; r < R_PB; ++r) {
                const float* rr = rl + r * D_IN + d4 * 4;   // LDS broadcast
                I[r] += wv.x * rr[0] + wv.y * rr[1] + wv.z * rr[2] + wv.w * rr[3];
            }
        }
        // state load + initial f16 spikes
        half8 s0;
        #pragma unroll
        for (int r = 0; r < R_PB; ++r) {
            c0v[r] = cin[(size_t)(r0 + r) * N_NEU + n];
            v0v[r] = vin[(size_t)(r0 + r) * N_NEU + n];
            ssum[r] = 0.f;
            s0[r] = (c0v[r] > 0.f) ? (_Float16)1 : (_Float16)0;
        }
        __syncthreads();   // rl reads done before spk/recx region reuse
        *(half8*)(smem + spk_n) = s0;
    } else {
        __syncthreads();   // matching barrier
    }

    const float AS   = (float)0.8187307530779818;   // exp(-1/5)
    const float OMAS = (float)(1.0 - 0.8187307530779818);
    const float AM   = (float)0.9512294245007140;   // exp(-1/20)
    const float OMAM = (float)(1.0 - 0.9512294245007140);

    int T = nsteps_p[0];
    __syncthreads();

    #pragma unroll 1
    for (int t = 0; t < T; ++t) {
        float rec[R_PB];
        #pragma unroll
        for (int r = 0; r < R_PB; ++r) rec[r] = 0.f;

        const char* ip = ip0;
        const char* wp = wp0;
        #pragma unroll 1
        for (int it = 0; it < nit; ++it) {
            uint4  X  = *(const uint4*)ip;           // 8 swizzled offsets
            float4 Wa = ((const float4*)wp)[0];      // 8 exact f32 weights
            float4 Wb = ((const float4*)wp)[1];
            ip += 2048; wp += 4096;
            half8 s0 = *(const half8*)(smem + (X.x & 0xffffu));
            half8 s1 = *(const half8*)(smem + (X.x >> 16));
            half8 s2 = *(const half8*)(smem + (X.y & 0xffffu));
            half8 s3 = *(const half8*)(smem + (X.y >> 16));
            half8 s4 = *(const half8*)(smem + (X.z & 0xffffu));
            half8 s5 = *(const half8*)(smem + (X.z >> 16));
            half8 s6 = *(const half8*)(smem + (X.w & 0xffffu));
            half8 s7 = *(const half8*)(smem + (X.w >> 16));
            #pragma unroll
            for (int r = 0; r < R_PB; ++r) {
                float a = rec[r];
                a = fmaf(Wa.x, (float)s0[r], a);
                a = fmaf(Wa.y, (float)s1[r], a);
                a = fmaf(Wa.z, (float)s2[r], a);
                a = fmaf(Wa.w, (float)s3[r], a);
                a = fmaf(Wb.x, (float)s4[r], a);
                a = fmaf(Wb.y, (float)s5[r], a);
                a = fmaf(Wb.z, (float)s6[r], a);
                a = fmaf(Wb.w, (float)s7[r], a);
                rec[r] = a;
            }
        }

        if (h == 1) {
            float* rx = recx + (size_t)q * 8;
            *(float4*)rx       = make_float4(rec[0], rec[1], rec[2], rec[3]);
            *(float4*)(rx + 4) = make_float4(rec[4], rec[5], rec[6], rec[7]);
        }
        __syncthreads();   // half-1 partials visible; all spike reads done

        if (h == 0) {
            const float* rx = recx + (size_t)q * 8;
            half8 ns;
            #pragma unroll
            for (int r = 0; r < R_PB; ++r) {
                float rc = rec[r] + rx[r];
                c0v[r] = AS * c0v[r] + OMAS * (I[r] + rc);
                v0v[r] = AM * v0v[r] + OMAM * c0v[r];
                ssum[r] += (v0v[r] > 0.f) ? 1.f : 0.f;
                ns[r] = (c0v[r] > 0.f) ? (_Float16)1 : (_Float16)0;
            }
            *(half8*)(smem + spk_n) = ns;
        }
        __syncthreads();   // new spikes visible
    }

    if (h == 0) {
        float invT = 1.0f / (float)T;
        size_t BN = (size_t)B_ROWS * N_NEU;
        #pragma unroll
        for (int r = 0; r < R_PB; ++r) {
            size_t off = (size_t)(r0 + r) * N_NEU + n;
            out[off]          = ssum[r] * invT;   // readout
            out[BN + off]     = v0v[r];           // final v
            out[2 * BN + off] = c0v[r];           // final c
        }
    }
}

// ---------------------------------------------------------------- launch
extern "C" void kernel_launch(void* const* d_in, const int* in_sizes, int n_in,
                              void* d_out, int out_size, void* d_ws, size_t ws_size,
                              hipStream_t stream)
{
    const float* rates = (const float*)d_in[0];
    const float* inW   = (const float*)d_in[1];
    const float* W     = (const float*)d_in[2];
    const float* vin   = (const float*)d_in[3];
    const float* cin   = (const float*)d_in[4];
    const int*   nst   = (const int*)d_in[5];
    uint32_t* ws = (uint32_t*)d_ws;
    float* out = (float*)d_out;
    (void)in_sizes; (void)n_in; (void)out_size; (void)ws_size;

    // zero CNT (harness poisons d_ws to 0xAA before every call)
    hipMemsetAsync((char*)d_ws + WS_CNT, 0, 2048, stream);

    lsm_count<<<128, 256, 0, stream>>>(W, ws);
    lsm_sort<<<1, 512, 0, stream>>>(ws);
    lsm_fill<<<N_NEU, 64, 0, stream>>>(W, ws);
    lsm_main<<<NBLK, 1024, 0, stream>>>(rates, inW, vin, cin, nst, ws, out);
}

// Round 8
// 411.601 us; speedup vs baseline: 2.3131x; 2.2880x over previous
//
#include <hip/hip_runtime.h>
#include <stdint.h>

// LiquidStateMachine on MI355X — round 8.
// History: r5 (366us) = f16x8 spike records @16k, ds_read_b128 gathers,
// LDS-bound with 45% conflicts. r6/r7 (~900us) proved the bank swizzle
// breaks b128 alignment -> misaligned-gather replay catastrophe. A
// 16B-aligned b128 can only start on 8 of 32 banks -> unfixable by
// swizzle. r8 lever: HALVE gather bytes. Spike record = 8 rows x u8 0/1
// = 8 B at natural offset 8k -> ds_read_b64 (aligned), bank-starts on 16
// even banks (~4-way, mild). Unpack = v_cvt_f32_ubyteN + v_fma (2 VALU
// per row-entry; VALU was not the binding pipe in r5). Everything else
// identical to r5's proven structure.
// Weights EXACT fp32 (r2: rounding flips spikes); u8 spike 0/1 exact.
//
// d_ws layout (bytes):
//   0      PERM[512]  sorted-rank -> column
//   2048   RANK[512]  column -> sorted rank
//   4096   CNT[512]   nnz per column          (zeroed via hipMemsetAsync)
//   8192   CNTW[8]    per-group padded trip count (multiple of 16)
//   8256   IBASE[8]   per-group byte base into IDX region
//   8320   WBASE[8]   per-group byte base into WT region
//   16384  IDX        u16 spike-offset (8k):
//                     byte = ib + (j>>3)*1024 + ls*16 + (j&7)*2
//   81920  WT         f32 w: byte = wb + (j>>3)*2048 + ls*32 + (j&7)*4

#define N_NEU 512
#define B_ROWS 2048
#define D_IN 256
#define R_PB 8
#define NBLK (B_ROWS / R_PB)   // 256 blocks x 1024 threads = 1 block/CU

#define WS_PERM    0
#define WS_RANK    2048
#define WS_CNT     4096
#define WS_CNTW    8192
#define WS_IBASE   8256
#define WS_WBASE   8320
#define WS_IDX     16384
#define WS_WT      81920

// spike record: 8 bytes (8 rows x u8 0/1) at natural offset 8k
#define SPK_OFF(k)  ((k) << 3)
#define SPK_REGION  4096       // 512 neurons x 8 B

// ---------------------------------------------------------------- prep A
__global__ __launch_bounds__(256) void lsm_count(
    const float* __restrict__ W, uint32_t* __restrict__ ws)
{
    int t  = threadIdx.x;
    int k0 = blockIdx.x * 4;
    int c0 = 0, c1 = 0;
    #pragma unroll
    for (int kk = 0; kk < 4; ++kk) {
        const float* row = W + (size_t)(k0 + kk) * N_NEU;
        c0 += (row[t]       != 0.0f) ? 1 : 0;
        c1 += (row[t + 256] != 0.0f) ? 1 : 0;
    }
    if (c0) atomicAdd(&ws[(WS_CNT >> 2) + t],       (uint32_t)c0);
    if (c1) atomicAdd(&ws[(WS_CNT >> 2) + t + 256], (uint32_t)c1);
}

// ---------------------------------------------------------------- prep B
// Counting-sort columns ascending by nnz; per-group padded trip counts
// (multiple of 16: both stream-halves get whole 8-entry chunks) + bases;
// pad entries (offset 0 -> reads neuron 0's record, w=+0.0f -> adds 0).
__global__ __launch_bounds__(512) void lsm_sort(uint32_t* __restrict__ ws)
{
    __shared__ int hist[N_NEU + 1];
    __shared__ int csort[N_NEU];
    __shared__ int gcw[8];

    int t = threadIdx.x;
    int creal = (int)ws[(WS_CNT >> 2) + t];
    for (int i = t; i < N_NEU + 1; i += 512) hist[i] = 0;
    __syncthreads();
    atomicAdd(&hist[creal], 1);
    __syncthreads();
    if (t == 0) {
        int acc = 0;
        for (int v = 0; v <= N_NEU; ++v) { int h = hist[v]; hist[v] = acc; acc += h; }
    }
    __syncthreads();
    int rank = atomicAdd(&hist[creal], 1);
    ws[(WS_PERM >> 2) + rank] = (uint32_t)t;
    ws[(WS_RANK >> 2) + t]    = (uint32_t)rank;
    csort[rank] = creal;
    __syncthreads();
    if (t < 8) {
        int cw = csort[t * 64 + 63];         // ascending -> group max is last
        cw = (cw + 15) & ~15;                // pad to multiple of 16
        gcw[t] = cw;
        ws[(WS_CNTW >> 2) + t] = (uint32_t)cw;
    }
    __syncthreads();
    if (t == 0) {
        int ai = 0, aw = 0;
        for (int g = 0; g < 8; ++g) {
            ws[(WS_IBASE >> 2) + g] = (uint32_t)ai;
            ws[(WS_WBASE >> 2) + g] = (uint32_t)aw;
            ai += gcw[g] * 64 * 2;           // bytes (u16 per entry)
            aw += gcw[g] * 64 * 4;           // bytes (f32 per entry)
        }
    }
    __syncthreads();
    // pad tail slots of this thread's column
    int wg = rank >> 6, ls = rank & 63;
    int cw = gcw[wg];
    uint32_t ib = ws[(WS_IBASE >> 2) + wg];
    uint32_t wb = ws[(WS_WBASE >> 2) + wg];
    char* base = (char*)ws;
    for (int j = creal; j < cw; ++j) {
        *(unsigned short*)(base + WS_IDX + ib + (j >> 3) * 1024 + ls * 16 + (j & 7) * 2) = 0;
        *(float*)(base + WS_WT + wb + (j >> 3) * 2048 + ls * 32 + (j & 7) * 4) = 0.0f;
    }
}

// ---------------------------------------------------------------- prep C
// One block per COLUMN, LDS-local cursor. Index stored as FINAL LDS byte
// offset (8k) of neuron k's spike record -> zero address math in main.
__global__ __launch_bounds__(64) void lsm_fill(
    const float* __restrict__ W, uint32_t* __restrict__ ws)
{
    int c    = blockIdx.x;
    int lane = threadIdx.x;
    char* base = (char*)ws;
    uint32_t rank = ws[(WS_RANK >> 2) + c];
    int wg = (int)(rank >> 6), ls = (int)(rank & 63);
    uint32_t ib = ws[(WS_IBASE >> 2) + wg];
    uint32_t wb = ws[(WS_WBASE >> 2) + wg];

    __shared__ int ctr;
    if (lane == 0) ctr = 0;
    __syncthreads();

    for (int k = lane; k < N_NEU; k += 64) {
        float wv = W[(size_t)k * N_NEU + c];
        if (wv != 0.0f) {
            int j = atomicAdd(&ctr, 1);      // order within column irrelevant
            *(unsigned short*)(base + WS_IDX + ib + (j >> 3) * 1024 + ls * 16 + (j & 7) * 2)
                = (unsigned short)SPK_OFF(k);
            *(float*)(base + WS_WT + wb + (j >> 3) * 2048 + ls * 32 + (j & 7) * 4) = wv;
        }
    }
}

// extract row r's spike (0.0f or 1.0f) from an 8-byte record {lo,hi}
// pattern (float)((dw >> 8j) & 0xff) folds to v_cvt_f32_ubyteN (1 VALU op)
__device__ __forceinline__ float spk_row(uint2 s, int r) {
    unsigned dw = (r < 4) ? s.x : s.y;
    return (float)((dw >> ((r & 3) * 8)) & 0xffu);
}

// ---------------------------------------------------------------- main
// LDS map:
//   [0,4096)       spk : u8 [8 rows] per neuron, 8 B records at 8k
//                  (at offset 0 so gather addr == precomputed stream value)
//   [4096,20480)   recx: float[512 cols][8] (half-1 partial rec)
//                  rl  : overlay at 4096, rates staging [8][256] (pre-loop)
__global__ __launch_bounds__(1024, 4) void lsm_main(
    const float* __restrict__ rates, const float* __restrict__ inW,
    const float* __restrict__ vin,   const float* __restrict__ cin,
    const int* __restrict__ nsteps_p,
    const uint32_t* __restrict__ ws, float* __restrict__ out)
{
    __shared__ __align__(16) unsigned char smem[SPK_REGION + 16384];
    float* recx = (float*)(smem + SPK_REGION);
    float* rl   = (float*)(smem + SPK_REGION);   // overlay, pre-loop only

    int p    = threadIdx.x;
    int h    = p >> 9;          // stream half: 0 or 1
    int q    = p & 511;         // column slot
    int blk  = blockIdx.x;
    int r0   = blk * R_PB;
    int wg   = q >> 6;
    int lane = q & 63;
    int n    = (int)ws[(WS_PERM >> 2) + q];
    int cw   = (int)ws[(WS_CNTW >> 2) + wg];     // wave-uniform
    int nit  = cw >> 4;                          // 8-entry chunks per half
    const char* ip0 = (const char*)ws + WS_IDX + ws[(WS_IBASE >> 2) + wg]
                    + h * 1024 + lane * 16;
    const char* wp0 = (const char*)ws + WS_WT  + ws[(WS_WBASE >> 2) + wg]
                    + h * 2048 + lane * 32;
    int spk_n = SPK_OFF(n);                      // this column's record

    // stage this block's 8 rate rows (2048 floats = 512 float4)
    if (p < 512)
        ((float4*)rl)[p] = ((const float4*)(rates + (size_t)r0 * D_IN))[p];
    __syncthreads();

    float c0v[R_PB], v0v[R_PB], ssum[R_PB], I[R_PB];
    if (h == 0) {
        // input current I[r] = rates[r,:] . inW[n,:] (constant across steps)
        #pragma unroll
        for (int r = 0; r < R_PB; ++r) I[r] = 0.f;
        const float4* wrow = (const float4*)(inW + (size_t)n * D_IN);
        for (int d4 = 0; d4 < D_IN / 4; ++d4) {
            float4 wv = wrow[d4];
            #pragma unroll
            for (int r = 0; r < R_PB; ++r) {
                const float* rr = rl + r * D_IN + d4 * 4;   // LDS broadcast
                I[r] += wv.x * rr[0] + wv.y * rr[1] + wv.z * rr[2] + wv.w * rr[3];
            }
        }
        // state load + initial u8 spikes
        uint2 s0 = make_uint2(0u, 0u);
        #pragma unroll
        for (int r = 0; r < R_PB; ++r) {
            c0v[r] = cin[(size_t)(r0 + r) * N_NEU + n];
            v0v[r] = vin[(size_t)(r0 + r) * N_NEU + n];
            ssum[r] = 0.f;
            unsigned bit = (c0v[r] > 0.f) ? 1u : 0u;
            if (r < 4) s0.x |= bit << (r * 8);
            else       s0.y |= bit << ((r - 4) * 8);
        }
        __syncthreads();   // rl reads done before spk/recx region reuse
        *(uint2*)(smem + spk_n) = s0;
    } else {
        __syncthreads();   // matching barrier
    }

    const float AS   = (float)0.8187307530779818;   // exp(-1/5)
    const float OMAS = (float)(1.0 - 0.8187307530779818);
    const float AM   = (float)0.9512294245007140;   // exp(-1/20)
    const float OMAM = (float)(1.0 - 0.9512294245007140);

    int T = nsteps_p[0];
    __syncthreads();

    #pragma unroll 1
    for (int t = 0; t < T; ++t) {
        float rec[R_PB];
        #pragma unroll
        for (int r = 0; r < R_PB; ++r) rec[r] = 0.f;

        const char* ip = ip0;
        const char* wp = wp0;
        #pragma unroll 1
        for (int it = 0; it < nit; ++it) {
            uint4  X  = *(const uint4*)ip;           // 8 u16 spike offsets
            float4 Wa = ((const float4*)wp)[0];      // 8 exact f32 weights
            float4 Wb = ((const float4*)wp)[1];
            ip += 2048; wp += 4096;
            uint2 s0 = *(const uint2*)(smem + (X.x & 0xffffu));
            uint2 s1 = *(const uint2*)(smem + (X.x >> 16));
            uint2 s2 = *(const uint2*)(smem + (X.y & 0xffffu));
            uint2 s3 = *(const uint2*)(smem + (X.y >> 16));
            uint2 s4 = *(const uint2*)(smem + (X.z & 0xffffu));
            uint2 s5 = *(const uint2*)(smem + (X.z >> 16));
            uint2 s6 = *(const uint2*)(smem + (X.w & 0xffffu));
            uint2 s7 = *(const uint2*)(smem + (X.w >> 16));
            #pragma unroll
            for (int r = 0; r < R_PB; ++r) {
                float a = rec[r];
                a = fmaf(Wa.x, spk_row(s0, r), a);
                a = fmaf(Wa.y, spk_row(s1, r), a);
                a = fmaf(Wa.z, spk_row(s2, r), a);
                a = fmaf(Wa.w, spk_row(s3, r), a);
                a = fmaf(Wb.x, spk_row(s4, r), a);
                a = fmaf(Wb.y, spk_row(s5, r), a);
                a = fmaf(Wb.z, spk_row(s6, r), a);
                a = fmaf(Wb.w, spk_row(s7, r), a);
                rec[r] = a;
            }
        }

        if (h == 1) {
            float* rx = recx + (size_t)q * 8;
            *(float4*)rx       = make_float4(rec[0], rec[1], rec[2], rec[3]);
            *(float4*)(rx + 4) = make_float4(rec[4], rec[5], rec[6], rec[7]);
        }
        __syncthreads();   // half-1 partials visible; all spike reads done

        if (h == 0) {
            const float* rx = recx + (size_t)q * 8;
            uint2 ns = make_uint2(0u, 0u);
            #pragma unroll
            for (int r = 0; r < R_PB; ++r) {
                float rc = rec[r] + rx[r];
                c0v[r] = AS * c0v[r] + OMAS * (I[r] + rc);
                v0v[r] = AM * v0v[r] + OMAM * c0v[r];
                ssum[r] += (v0v[r] > 0.f) ? 1.f : 0.f;
                unsigned bit = (c0v[r] > 0.f) ? 1u : 0u;
                if (r < 4) ns.x |= bit << (r * 8);
                else       ns.y |= bit << ((r - 4) * 8);
            }
            *(uint2*)(smem + spk_n) = ns;
        }
        __syncthreads();   // new spikes visible
    }

    if (h == 0) {
        float invT = 1.0f / (float)T;
        size_t BN = (size_t)B_ROWS * N_NEU;
        #pragma unroll
        for (int r = 0; r < R_PB; ++r) {
            size_t off = (size_t)(r0 + r) * N_NEU + n;
            out[off]          = ssum[r] * invT;   // readout
            out[BN + off]     = v0v[r];           // final v
            out[2 * BN + off] = c0v[r];           // final c
        }
    }
}

// ---------------------------------------------------------------- launch
extern "C" void kernel_launch(void* const* d_in, const int* in_sizes, int n_in,
                              void* d_out, int out_size, void* d_ws, size_t ws_size,
                              hipStream_t stream)
{
    const float* rates = (const float*)d_in[0];
    const float* inW   = (const float*)d_in[1];
    const float* W     = (const float*)d_in[2];
    const float* vin   = (const float*)d_in[3];
    const float* cin   = (const float*)d_in[4];
    const int*   nst   = (const int*)d_in[5];
    uint32_t* ws = (uint32_t*)d_ws;
    float* out = (float*)d_out;
    (void)in_sizes; (void)n_in; (void)out_size; (void)ws_size;

    // zero CNT (harness poisons d_ws to 0xAA before every call)
    hipMemsetAsync((char*)d_ws + WS_CNT, 0, 2048, stream);

    lsm_count<<<128, 256, 0, stream>>>(W, ws);
    lsm_sort<<<1, 512, 0, stream>>>(ws);
    lsm_fill<<<N_NEU, 64, 0, stream>>>(W, ws);
    lsm_main<<<NBLK, 1024, 0, stream>>>(rates, inW, vin, cin, nst, ws, out);
}